// Round 5
// baseline (105.895 us; speedup 1.0000x reference)
//
#include <hip/hip_runtime.h>

typedef _Float16 f16;
typedef _Float16 f16x8 __attribute__((ext_vector_type(8)));
typedef _Float16 f16x4 __attribute__((ext_vector_type(4)));
typedef float f32x4 __attribute__((ext_vector_type(4)));

#define GAS(p) ((const __attribute__((address_space(1))) void*)(p))
#define LAS(p) ((__attribute__((address_space(3))) void*)(p))

__device__ __forceinline__ f32x4 mfma16(f16x8 a, f16x8 b, f32x4 c) {
  return __builtin_amdgcn_mfma_f32_16x16x32_f16(a, b, c, 0, 0, 0);
}

// Stage one 16B chunk per thread into a swizzled LDS tile.
// LDS slot u of row r holds logical col-slot u^(r&7); achieved by linear LDS
// dest + inverse-swizzled global source (rule: both-sides-or-neither).
__device__ __forceinline__ void stage_tile(const f16* __restrict__ grow0,
                                           int stride_f16, f16* lds, int t) {
  int r = t >> 3;
  int sw = ((t & 7) ^ (r & 7)) * 8;
  __builtin_amdgcn_global_load_lds(GAS(grow0 + r * stride_f16 + sw),
                                   LAS(lds + t * 8), 16, 0, 0);
}

// ---------------- fused fp32->fp16 converts + RoPE tables ----------------
__global__ void convall(const float* __restrict__ x, const float* __restrict__ wq,
                        const float* __restrict__ wk, const float* __restrict__ wv,
                        f16* __restrict__ xh, f16* __restrict__ wh,
                        float* __restrict__ cosT, float* __restrict__ sinT) {
  int bid = blockIdx.x;
  if (bid >= 3584) {  // RoPE tables [2048][32]
    int idx = (bid - 3584) * 256 + threadIdx.x;
    int n = idx >> 5, jj = idx & 31;
    float inv = powf(10000.0f, -(float)jj * (1.0f / 32.0f));
    float ang = (float)n * inv;
    cosT[idx] = cosf(ang);
    sinT[idx] = sinf(ang);
    return;
  }
  const float* s;
  f16* d;
  int boff;
  if (bid < 2048)      { s = x;  d = xh;            boff = bid; }
  else if (bid < 2560) { s = wq; d = wh;            boff = bid - 2048; }
  else if (bid < 3072) { s = wk; d = wh + 1048576;  boff = bid - 2560; }
  else                 { s = wv; d = wh + 2097152;  boff = bid - 3072; }
  int i = (boff * 256 + threadIdx.x) * 8;
  float4 a = *(const float4*)(s + i);
  float4 b = *(const float4*)(s + i + 4);
  f16x8 o = {(f16)a.x, (f16)a.y, (f16)a.z, (f16)a.w,
             (f16)b.x, (f16)b.y, (f16)b.z, (f16)b.w};
  *(f16x8*)(d + i) = o;
}

// ---------------- fused QKV GEMM + RoPE epilogue ----------------
// X: [4096][1024] f16, W: [3072][1024] f16 (Wq|Wk|Wv stacked)
// Q,K out: [32][2048][64] (RoPE applied, Q pre-scaled by log2e/8)
// Vt out:  [32][64][2048]
__global__ __launch_bounds__(256, 3) void qkv_gemm(
    const f16* __restrict__ X, const f16* __restrict__ W,
    const float* __restrict__ cosT, const float* __restrict__ sinT,
    f16* __restrict__ Q, f16* __restrict__ K, f16* __restrict__ Vt) {
  __shared__ f16 As[128 * 64];
  __shared__ f16 Bs[128 * 64];
  const int tid = threadIdx.x;
  const int wv = tid >> 6, lane = tid & 63;
  const int m0 = blockIdx.x * 128, n0 = blockIdx.y * 128;
  const int cl = lane & 15, g = lane >> 4;
  const int wr = (wv >> 1) * 64, wc = (wv & 1) * 64;
  const int vx = cl & 7;

  f32x4 acc[4][4] = {};
  const f16* ga = X + (size_t)m0 * 1024;
  const f16* gb = W + (size_t)n0 * 1024;

  for (int kt = 0; kt < 1024; kt += 64) {
    __syncthreads();
#pragma unroll
    for (int rd = 0; rd < 4; ++rd) {
      stage_tile(ga + kt, 1024, As, tid + rd * 256);
      stage_tile(gb + kt, 1024, Bs, tid + rd * 256);
    }
    __syncthreads();  // compiler drains vmcnt before barrier
#pragma unroll
    for (int kk = 0; kk < 2; ++kk) {
      f16x8 a[4], bf[4];
#pragma unroll
      for (int mi = 0; mi < 4; ++mi)
        a[mi] = *(const f16x8*)(As + (wr + mi * 16 + cl) * 64 +
                                (((kk * 4 + g) ^ vx) << 3));
#pragma unroll
      for (int ni = 0; ni < 4; ++ni)
        bf[ni] = *(const f16x8*)(Bs + (wc + ni * 16 + cl) * 64 +
                                 (((kk * 4 + g) ^ vx) << 3));
#pragma unroll
      for (int mi = 0; mi < 4; ++mi)
#pragma unroll
        for (int ni = 0; ni < 4; ++ni)
          acc[mi][ni] = mfma16(a[mi], bf[ni], acc[mi][ni]);
    }
  }

  // epilogue: C/D layout col=lane&15 row=(lane>>4)*4+reg
  const int p = n0 >> 10;  // 0=q 1=k 2=v
  for (int mi = 0; mi < 4; ++mi) {
    int rbase = m0 + wr + mi * 16 + g * 4;
    for (int ni = 0; ni < 4; ++ni) {
      int gc = n0 + wc + ni * 16 + cl;
      int f = gc & 1023;
      int h = f >> 6, d = f & 63;
      if (p < 2) {
        int j = d >> 1;
        f16* dst = (p == 0) ? Q : K;
        // Q pre-scale folds softmax 1/8 and log2(e) (exp2-domain scores)
        float sc = (p == 0) ? 0.18033688011f : 1.0f;
        for (int r = 0; r < 4; ++r) {
          int row = rbase + r;
          int bb = row >> 11, n = row & 2047;
          float co = cosT[n * 32 + j], si = sinT[n * 32 + j];
          float v = acc[mi][ni][r];
          float pr = __shfl_xor(v, 1);
          float o = (d & 1) ? (v * co + pr * si) : (v * co - pr * si);
          dst[((bb * 16 + h) * 2048 + n) * 64 + d] = (f16)(o * sc);
        }
      } else {
        int bb = rbase >> 11, n = rbase & 2047;
        f16x4 pk = {(f16)acc[mi][ni][0], (f16)acc[mi][ni][1],
                    (f16)acc[mi][ni][2], (f16)acc[mi][ni][3]};
        *(f16x4*)(Vt + (size_t)((bb * 16 + h) * 64 + d) * 2048 + n) = pk;
      }
    }
  }
}

// ---------------- flash attention fwd v5 ----------------
// grid 512 x 256 thr; block = 128 q (4 waves x 32 q), KVBLK=64, 2 blocks/CU.
// Each wave owns TWO 16-q column fragments sharing the same K/V fragments:
// halves per-q LDS read volume vs v4. Static-max softmax p = 2^s (scale-
// invariant, no bias needed). P fully in-register via permuted k-slots.
__global__ __launch_bounds__(256, 2) void attn(
    const f16* __restrict__ Q, const f16* __restrict__ K,
    const f16* __restrict__ Vt, float* __restrict__ out) {
  __shared__ f16 Ks[2][64 * 64];   // [key][d], XOR-swizzled 16B slots
  __shared__ f16 Vs[2][64 * 64];   // [d][key], XOR-swizzled 16B slots
  const int tid = threadIdx.x;
  const int w = tid >> 6, lane = tid & 63;
  const int cl = lane & 15, g = lane >> 4;
  const int id = blockIdx.x;
  const int xcd = id & 7, j = id >> 3;  // XCD-grouped: 4 bh per XCD
  const int bh = xcd * 4 + (j >> 4);
  const int b = bh >> 4, h = bh & 15;
  const int qb = (j & 15) * 128 + w * 32;  // wave's 32-q base
  const f16* Qp = Q + (size_t)bh * (2048 * 64);
  const f16* Kp = K + (size_t)bh * (2048 * 64);
  const f16* Vp = Vt + (size_t)bh * (64 * 2048);

  // Q as B-operand: col=q=cl (per half), k=d (pre-scaled by log2e/8)
  f16x8 bq[2][2];
#pragma unroll
  for (int qh = 0; qh < 2; ++qh) {
    bq[qh][0] = *(const f16x8*)(Qp + (qb + qh * 16 + cl) * 64 + g * 8);
    bq[qh][1] = *(const f16x8*)(Qp + (qb + qh * 16 + cl) * 64 + 32 + g * 8);
  }

  f32x4 acc[2][4] = {};   // acc[qh][dblk]: O^T[d=dblk*16+g*4+r][q]
  float lsp[2] = {0.f, 0.f};
  const int vx = cl & 15 & 7;
  const int g2 = g >> 1, go = (g & 1) * 4;

  stage_tile(Kp, 64, Ks[0], tid);
  stage_tile(Kp, 64, Ks[0], tid + 256);
  stage_tile(Vp, 2048, Vs[0], tid);
  stage_tile(Vp, 2048, Vs[0], tid + 256);

  for (int it = 0; it < 32; ++it) {
    const int cur = it & 1;
    asm volatile("s_waitcnt vmcnt(0)" ::: "memory");
    __builtin_amdgcn_s_barrier();
    if (it + 1 < 32) {
      const f16* kn = Kp + (size_t)(it + 1) * 64 * 64;
      const f16* vn = Vp + (size_t)(it + 1) * 64;
      stage_tile(kn, 64, Ks[cur ^ 1], tid);
      stage_tile(kn, 64, Ks[cur ^ 1], tid + 256);
      stage_tile(vn, 2048, Vs[cur ^ 1], tid);
      stage_tile(vn, 2048, Vs[cur ^ 1], tid + 256);
    }
    // ---- K fragments (shared by both q-halves) ----
    const f16* kb = Ks[cur];
    f16x8 a0[4], a1[4];
#pragma unroll
    for (int i = 0; i < 4; ++i) {
      const f16* kr = kb + (i * 16 + cl) * 64;
      a0[i] = *(const f16x8*)(kr + ((g ^ vx) << 3));
      a1[i] = *(const f16x8*)(kr + (((4 + g) ^ vx) << 3));
    }
    // ---- QK^T (swapped): s[qh][i] rows = keys i*16+g*4+r, col = q ----
    f32x4 s[2][4];
    __builtin_amdgcn_s_setprio(1);
#pragma unroll
    for (int qh = 0; qh < 2; ++qh)
#pragma unroll
      for (int i = 0; i < 4; ++i) {
        f32x4 t0 = {};
        t0 = mfma16(a0[i], bq[qh][0], t0);
        s[qh][i] = mfma16(a1[i], bq[qh][1], t0);
      }
    __builtin_amdgcn_s_setprio(0);
    // ---- static-max softmax: p = 2^s, in-register ----
    f16x4 wi[2][4];
#pragma unroll
    for (int qh = 0; qh < 2; ++qh) {
      float ps = 0.f;
#pragma unroll
      for (int i = 0; i < 4; ++i) {
        float p0 = exp2f(s[qh][i][0]);
        float p1 = exp2f(s[qh][i][1]);
        float p2 = exp2f(s[qh][i][2]);
        float p3 = exp2f(s[qh][i][3]);
        ps += (p0 + p1) + (p2 + p3);
        wi[qh][i] = {(f16)p0, (f16)p1, (f16)p2, (f16)p3};
      }
      lsp[qh] += ps;
    }
    // ---- PV with permuted k-slots; V frags shared by both q-halves ----
    const f16* vb = Vs[cur];
    __builtin_amdgcn_s_setprio(1);
#pragma unroll
    for (int ks = 0; ks < 2; ++ks) {
      f16x8 pb0 = {wi[0][2 * ks][0], wi[0][2 * ks][1], wi[0][2 * ks][2],
                   wi[0][2 * ks][3], wi[0][2 * ks + 1][0], wi[0][2 * ks + 1][1],
                   wi[0][2 * ks + 1][2], wi[0][2 * ks + 1][3]};
      f16x8 pb1 = {wi[1][2 * ks][0], wi[1][2 * ks][1], wi[1][2 * ks][2],
                   wi[1][2 * ks][3], wi[1][2 * ks + 1][0], wi[1][2 * ks + 1][1],
                   wi[1][2 * ks + 1][2], wi[1][2 * ks + 1][3]};
#pragma unroll
      for (int d = 0; d < 4; ++d) {
        const f16* vr = vb + (d * 16 + cl) * 64;
        f16x4 lo = *(const f16x4*)(vr + (((ks * 4 + g2) ^ vx) << 3) + go);
        f16x4 hi = *(const f16x4*)(vr + (((ks * 4 + 2 + g2) ^ vx) << 3) + go);
        f16x8 va = {lo[0], lo[1], lo[2], lo[3], hi[0], hi[1], hi[2], hi[3]};
        acc[0][d] = mfma16(va, pb0, acc[0][d]);
        acc[1][d] = mfma16(va, pb1, acc[1][d]);
      }
    }
    __builtin_amdgcn_s_setprio(0);
  }

#pragma unroll
  for (int qh = 0; qh < 2; ++qh) {
    float ls = lsp[qh];
    ls += __shfl_xor(ls, 16);
    ls += __shfl_xor(ls, 32);
    float inv = 1.0f / ls;
    float* ob = out + (size_t)(b * 2048 + qb + qh * 16 + cl) * 1024 +
                h * 64 + g * 4;
#pragma unroll
    for (int d = 0; d < 4; ++d) {
      float4 o = {acc[qh][d][0] * inv, acc[qh][d][1] * inv,
                  acc[qh][d][2] * inv, acc[qh][d][3] * inv};
      *(float4*)(ob + (size_t)d * 16) = o;
    }
  }
}

extern "C" void kernel_launch(void* const* d_in, const int* in_sizes, int n_in,
                              void* d_out, int out_size, void* d_ws, size_t ws_size,
                              hipStream_t stream) {
  const float* x  = (const float*)d_in[0];
  const float* Wq = (const float*)d_in[1];
  const float* Wk = (const float*)d_in[2];
  const float* Wv = (const float*)d_in[3];
  float* out = (float*)d_out;
  char* ws = (char*)d_ws;

  f16* xh   = (f16*)(ws);                       // 8388608 B
  f16* wh   = (f16*)(ws + 8388608);             // 6291456 B
  f16* Qr   = (f16*)(ws + 14680064);            // 8388608 B
  f16* Kr   = (f16*)(ws + 23068672);            // 8388608 B
  f16* Vt   = (f16*)(ws + 31457280);            // 8388608 B
  float* cosT = (float*)(ws + 39845888);        // 262144 B
  float* sinT = (float*)(ws + 40108032);        // total ~40.4 MB

  convall<<<3840, 256, 0, stream>>>(x, Wq, Wk, Wv, xh, wh, cosT, sinT);

  dim3 g1(32, 24);
  qkv_gemm<<<g1, 256, 0, stream>>>(xh, wh, cosT, sinT, Qr, Kr, Vt);

  attn<<<512, 256, 0, stream>>>(Qr, Kr, Vt, out);
}

// Round 6
// 102.170 us; speedup vs baseline: 1.0365x; 1.0365x over previous
//
#include <hip/hip_runtime.h>

typedef _Float16 f16;
typedef _Float16 f16x2 __attribute__((ext_vector_type(2)));
typedef _Float16 f16x8 __attribute__((ext_vector_type(8)));
typedef _Float16 f16x4 __attribute__((ext_vector_type(4)));
typedef float f32x4 __attribute__((ext_vector_type(4)));

#define GAS(p) ((const __attribute__((address_space(1))) void*)(p))
#define LAS(p) ((__attribute__((address_space(3))) void*)(p))

__device__ __forceinline__ f32x4 mfma16(f16x8 a, f16x8 b, f32x4 c) {
  return __builtin_amdgcn_mfma_f32_16x16x32_f16(a, b, c, 0, 0, 0);
}

__device__ __forceinline__ f16x2 cvt2(float a, float b) {
  return __builtin_bit_cast(f16x2, __builtin_amdgcn_cvt_pkrtz(a, b));
}

// Stage one 16B chunk per thread into a swizzled LDS tile.
// LDS slot u of row r holds logical col-slot u^(r&7); achieved by linear LDS
// dest + inverse-swizzled global source (rule: both-sides-or-neither).
__device__ __forceinline__ void stage_tile(const f16* __restrict__ grow0,
                                           int stride_f16, f16* lds, int t) {
  int r = t >> 3;
  int sw = ((t & 7) ^ (r & 7)) * 8;
  __builtin_amdgcn_global_load_lds(GAS(grow0 + r * stride_f16 + sw),
                                   LAS(lds + t * 8), 16, 0, 0);
}

// ---------------- fused fp32->fp16 converts + RoPE tables ----------------
__global__ void convall(const float* __restrict__ x, const float* __restrict__ wq,
                        const float* __restrict__ wk, const float* __restrict__ wv,
                        f16* __restrict__ xh, f16* __restrict__ wh,
                        float* __restrict__ cosT, float* __restrict__ sinT) {
  int bid = blockIdx.x;
  if (bid >= 3584) {  // RoPE tables [2048][32]
    int idx = (bid - 3584) * 256 + threadIdx.x;
    int n = idx >> 5, jj = idx & 31;
    float inv = powf(10000.0f, -(float)jj * (1.0f / 32.0f));
    float ang = (float)n * inv;
    cosT[idx] = cosf(ang);
    sinT[idx] = sinf(ang);
    return;
  }
  const float* s;
  f16* d;
  int boff;
  if (bid < 2048)      { s = x;  d = xh;            boff = bid; }
  else if (bid < 2560) { s = wq; d = wh;            boff = bid - 2048; }
  else if (bid < 3072) { s = wk; d = wh + 1048576;  boff = bid - 2560; }
  else                 { s = wv; d = wh + 2097152;  boff = bid - 3072; }
  int i = (boff * 256 + threadIdx.x) * 8;
  float4 a = *(const float4*)(s + i);
  float4 b = *(const float4*)(s + i + 4);
  f16x8 o = {(f16)a.x, (f16)a.y, (f16)a.z, (f16)a.w,
             (f16)b.x, (f16)b.y, (f16)b.z, (f16)b.w};
  *(f16x8*)(d + i) = o;
}

// ---------------- fused QKV GEMM + RoPE epilogue ----------------
// X: [4096][1024] f16, W: [3072][1024] f16 (Wq|Wk|Wv stacked)
// Q,K out: [32][2048][64] (RoPE applied, Q pre-scaled by log2e/8)
// Vt out:  [32][64][2048] with PERMUTED key coord n' = 32a+8c+4b+r
// (n = 32a+16b+4c+r) so attn's PV A-fragment is one contiguous b128.
__global__ __launch_bounds__(256, 3) void qkv_gemm(
    const f16* __restrict__ X, const f16* __restrict__ W,
    const float* __restrict__ cosT, const float* __restrict__ sinT,
    f16* __restrict__ Q, f16* __restrict__ K, f16* __restrict__ Vt) {
  __shared__ f16 As[128 * 64];
  __shared__ f16 Bs[128 * 64];
  const int tid = threadIdx.x;
  const int wv = tid >> 6, lane = tid & 63;
  const int m0 = blockIdx.x * 128, n0 = blockIdx.y * 128;
  const int cl = lane & 15, g = lane >> 4;
  const int wr = (wv >> 1) * 64, wc = (wv & 1) * 64;
  const int vx = cl & 7;

  f32x4 acc[4][4] = {};
  const f16* ga = X + (size_t)m0 * 1024;
  const f16* gb = W + (size_t)n0 * 1024;

  for (int kt = 0; kt < 1024; kt += 64) {
    __syncthreads();
#pragma unroll
    for (int rd = 0; rd < 4; ++rd) {
      stage_tile(ga + kt, 1024, As, tid + rd * 256);
      stage_tile(gb + kt, 1024, Bs, tid + rd * 256);
    }
    __syncthreads();  // compiler drains vmcnt before barrier
#pragma unroll
    for (int kk = 0; kk < 2; ++kk) {
      f16x8 a[4], bf[4];
#pragma unroll
      for (int mi = 0; mi < 4; ++mi)
        a[mi] = *(const f16x8*)(As + (wr + mi * 16 + cl) * 64 +
                                (((kk * 4 + g) ^ vx) << 3));
#pragma unroll
      for (int ni = 0; ni < 4; ++ni)
        bf[ni] = *(const f16x8*)(Bs + (wc + ni * 16 + cl) * 64 +
                                 (((kk * 4 + g) ^ vx) << 3));
#pragma unroll
      for (int mi = 0; mi < 4; ++mi)
#pragma unroll
        for (int ni = 0; ni < 4; ++ni)
          acc[mi][ni] = mfma16(a[mi], bf[ni], acc[mi][ni]);
    }
  }

  // epilogue: C/D layout col=lane&15 row=(lane>>4)*4+reg
  const int p = n0 >> 10;  // 0=q 1=k 2=v
  for (int mi = 0; mi < 4; ++mi) {
    int rbase = m0 + wr + mi * 16 + g * 4;
    for (int ni = 0; ni < 4; ++ni) {
      int gc = n0 + wc + ni * 16 + cl;
      int f = gc & 1023;
      int h = f >> 6, d = f & 63;
      if (p < 2) {
        int j = d >> 1;
        f16* dst = (p == 0) ? Q : K;
        // Q pre-scale folds softmax 1/8 and log2(e) (exp2-domain scores)
        float sc = (p == 0) ? 0.18033688011f : 1.0f;
        for (int r = 0; r < 4; ++r) {
          int row = rbase + r;
          int bb = row >> 11, n = row & 2047;
          float co = cosT[n * 32 + j], si = sinT[n * 32 + j];
          float v = acc[mi][ni][r];
          float pr = __shfl_xor(v, 1);
          float o = (d & 1) ? (v * co + pr * si) : (v * co - pr * si);
          dst[((bb * 16 + h) * 2048 + n) * 64 + d] = (f16)(o * sc);
        }
      } else {
        int bb = rbase >> 11, n = rbase & 2047;
        // permuted key coord (4-aligned block): n' = 32a | 8c | 4b
        int np = (n & ~31) | (((n >> 2) & 3) << 3) | (((n >> 4) & 1) << 2);
        f16x4 pk = {(f16)acc[mi][ni][0], (f16)acc[mi][ni][1],
                    (f16)acc[mi][ni][2], (f16)acc[mi][ni][3]};
        *(f16x4*)(Vt + (size_t)((bb * 16 + h) * 64 + d) * 2048 + np) = pk;
      }
    }
  }
}

// ---------------- flash attention fwd v6 ----------------
// grid 512 x 256 thr; block = 128 q (4 waves x 32 q), KVBLK=64.
// Triple-buffered K/V staging with counted vmcnt(4) (never drain in loop):
//   iter i: vmcnt(4) [tile i landed, in-order] ; barrier ; issue stage(i+2)
//           ; compute(i).  2-iteration prefetch window.
// Static-max softmax p = 2^s; P in-register; V key-permuted so PV A-frag
// is a single b128 read.
__global__ __launch_bounds__(256, 2) void attn(
    const f16* __restrict__ Q, const f16* __restrict__ K,
    const f16* __restrict__ Vt, float* __restrict__ out) {
  __shared__ f16 Ks[3][64 * 64];   // [key][d], XOR-swizzled 16B slots
  __shared__ f16 Vs[3][64 * 64];   // [d][key'], XOR-swizzled 16B slots
  const int tid = threadIdx.x;
  const int w = tid >> 6, lane = tid & 63;
  const int cl = lane & 15, g = lane >> 4;
  const int id = blockIdx.x;
  const int xcd = id & 7, j = id >> 3;  // XCD-grouped: 4 bh per XCD
  const int bh = xcd * 4 + (j >> 4);
  const int b = bh >> 4, h = bh & 15;
  const int qb = (j & 15) * 128 + w * 32;  // wave's 32-q base
  const f16* Qp = Q + (size_t)bh * (2048 * 64);
  const f16* Kp = K + (size_t)bh * (2048 * 64);
  const f16* Vp = Vt + (size_t)bh * (64 * 2048);

  // Q as B-operand: col=q=cl (per half), k=d (pre-scaled by log2e/8)
  f16x8 bq[2][2];
#pragma unroll
  for (int qh = 0; qh < 2; ++qh) {
    bq[qh][0] = *(const f16x8*)(Qp + (qb + qh * 16 + cl) * 64 + g * 8);
    bq[qh][1] = *(const f16x8*)(Qp + (qb + qh * 16 + cl) * 64 + 32 + g * 8);
  }

  f32x4 acc[2][4] = {};   // acc[qh][dblk]: O^T[d=dblk*16+g*4+r][q]
  float lsp[2] = {0.f, 0.f};
  const int vx = cl & 7;
  const f32x4 z4 = {0.f, 0.f, 0.f, 0.f};

  // prologue: stage tiles 0 and 1 (exactly 4 VMEM instrs per tile per wave)
  stage_tile(Kp, 64, Ks[0], tid);
  stage_tile(Kp, 64, Ks[0], tid + 256);
  stage_tile(Vp, 2048, Vs[0], tid);
  stage_tile(Vp, 2048, Vs[0], tid + 256);
  stage_tile(Kp + 4096, 64, Ks[1], tid);
  stage_tile(Kp + 4096, 64, Ks[1], tid + 256);
  stage_tile(Vp + 64, 2048, Vs[1], tid);
  stage_tile(Vp + 64, 2048, Vs[1], tid + 256);

  int cur = 0;
  for (int it = 0; it < 32; ++it) {
    // tile `it` landed when outstanding <= 4 (vmcnt retires in order)
    if (it < 31)
      asm volatile("s_waitcnt vmcnt(4)" ::: "memory");
    else
      asm volatile("s_waitcnt vmcnt(0)" ::: "memory");
    __builtin_amdgcn_s_barrier();
    if (it + 2 < 32) {  // stage tile it+2 into buf (cur+2)%3 (2-iter window)
      int nb = (cur >= 1) ? cur - 1 : cur + 2;
      const f16* kn = Kp + (size_t)(it + 2) * 4096;
      const f16* vn = Vp + (size_t)(it + 2) * 64;
      stage_tile(kn, 64, Ks[nb], tid);
      stage_tile(kn, 64, Ks[nb], tid + 256);
      stage_tile(vn, 2048, Vs[nb], tid);
      stage_tile(vn, 2048, Vs[nb], tid + 256);
    }
    // ---- K fragments (shared by both q-halves) ----
    const f16* kb = Ks[cur];
    f16x8 a0[4], a1[4];
#pragma unroll
    for (int i = 0; i < 4; ++i) {
      const f16* kr = kb + (i * 16 + cl) * 64;
      a0[i] = *(const f16x8*)(kr + ((g ^ vx) << 3));
      a1[i] = *(const f16x8*)(kr + (((4 + g) ^ vx) << 3));
    }
    // ---- QK^T (swapped): s[qh][i] rows = keys i*16+g*4+r, col = q ----
    f32x4 s[2][4];
    __builtin_amdgcn_s_setprio(1);
#pragma unroll
    for (int qh = 0; qh < 2; ++qh)
#pragma unroll
      for (int i = 0; i < 4; ++i)
        s[qh][i] = mfma16(a1[i], bq[qh][1], mfma16(a0[i], bq[qh][0], z4));
    __builtin_amdgcn_s_setprio(0);
    // ---- static-max softmax p = 2^s; packed cvt into PV B-operands ----
    union PB { f16x8 v; f16x2 h[4]; };
    PB pbu[2][2];  // [qh][ks]
#pragma unroll
    for (int qh = 0; qh < 2; ++qh) {
      float ps = 0.f;
#pragma unroll
      for (int i = 0; i < 4; ++i) {
        float p0 = exp2f(s[qh][i][0]);
        float p1 = exp2f(s[qh][i][1]);
        float p2 = exp2f(s[qh][i][2]);
        float p3 = exp2f(s[qh][i][3]);
        ps += (p0 + p1) + (p2 + p3);
        pbu[qh][i >> 1].h[(i & 1) * 2] = cvt2(p0, p1);
        pbu[qh][i >> 1].h[(i & 1) * 2 + 1] = cvt2(p2, p3);
      }
      lsp[qh] += ps;
    }
    // ---- PV: single b128 A-frag per (ks,d) thanks to V key-permutation ----
    const f16* vb = Vs[cur];
    __builtin_amdgcn_s_setprio(1);
#pragma unroll
    for (int ks = 0; ks < 2; ++ks) {
#pragma unroll
      for (int d = 0; d < 4; ++d) {
        const f16* vr = vb + (d * 16 + cl) * 64;
        f16x8 va = *(const f16x8*)(vr + (((ks * 4 + g) ^ vx) << 3));
        acc[0][d] = mfma16(va, pbu[0][ks].v, acc[0][d]);
        acc[1][d] = mfma16(va, pbu[1][ks].v, acc[1][d]);
      }
    }
    __builtin_amdgcn_s_setprio(0);
    cur = (cur == 2) ? 0 : cur + 1;
  }

#pragma unroll
  for (int qh = 0; qh < 2; ++qh) {
    float ls = lsp[qh];
    ls += __shfl_xor(ls, 16);
    ls += __shfl_xor(ls, 32);
    float inv = 1.0f / ls;
    float* ob = out + (size_t)(b * 2048 + qb + qh * 16 + cl) * 1024 +
                h * 64 + g * 4;
#pragma unroll
    for (int d = 0; d < 4; ++d) {
      float4 o = {acc[qh][d][0] * inv, acc[qh][d][1] * inv,
                  acc[qh][d][2] * inv, acc[qh][d][3] * inv};
      *(float4*)(ob + (size_t)d * 16) = o;
    }
  }
}

extern "C" void kernel_launch(void* const* d_in, const int* in_sizes, int n_in,
                              void* d_out, int out_size, void* d_ws, size_t ws_size,
                              hipStream_t stream) {
  const float* x  = (const float*)d_in[0];
  const float* Wq = (const float*)d_in[1];
  const float* Wk = (const float*)d_in[2];
  const float* Wv = (const float*)d_in[3];
  float* out = (float*)d_out;
  char* ws = (char*)d_ws;

  f16* xh   = (f16*)(ws);                       // 8388608 B
  f16* wh   = (f16*)(ws + 8388608);             // 6291456 B
  f16* Qr   = (f16*)(ws + 14680064);            // 8388608 B
  f16* Kr   = (f16*)(ws + 23068672);            // 8388608 B
  f16* Vt   = (f16*)(ws + 31457280);            // 8388608 B
  float* cosT = (float*)(ws + 39845888);        // 262144 B
  float* sinT = (float*)(ws + 40108032);        // total ~40.4 MB

  convall<<<3840, 256, 0, stream>>>(x, Wq, Wk, Wv, xh, wh, cosT, sinT);

  dim3 g1(32, 24);
  qkv_gemm<<<g1, 256, 0, stream>>>(xh, wh, cosT, sinT, Qr, Kr, Vt);

  attn<<<512, 256, 0, stream>>>(Qr, Kr, Vt, out);
}

// Round 7
// 101.453 us; speedup vs baseline: 1.0438x; 1.0071x over previous
//
#include <hip/hip_runtime.h>

typedef _Float16 f16;
typedef _Float16 f16x2 __attribute__((ext_vector_type(2)));
typedef _Float16 f16x8 __attribute__((ext_vector_type(8)));
typedef _Float16 f16x4 __attribute__((ext_vector_type(4)));
typedef float f32x4 __attribute__((ext_vector_type(4)));

#define GAS(p) ((const __attribute__((address_space(1))) void*)(p))
#define LAS(p) ((__attribute__((address_space(3))) void*)(p))

__device__ __forceinline__ f32x4 mfma16(f16x8 a, f16x8 b, f32x4 c) {
  return __builtin_amdgcn_mfma_f32_16x16x32_f16(a, b, c, 0, 0, 0);
}

__device__ __forceinline__ f16x2 cvt2(float a, float b) {
  return __builtin_bit_cast(f16x2, __builtin_amdgcn_cvt_pkrtz(a, b));
}

// Stage one 16B chunk per thread into a swizzled LDS tile.
// LDS slot u of row r holds logical col-slot u^(r&7); achieved by linear LDS
// dest + inverse-swizzled global source (rule: both-sides-or-neither).
__device__ __forceinline__ void stage_tile(const f16* __restrict__ grow0,
                                           int stride_f16, f16* lds, int t) {
  int r = t >> 3;
  int sw = ((t & 7) ^ (r & 7)) * 8;
  __builtin_amdgcn_global_load_lds(GAS(grow0 + r * stride_f16 + sw),
                                   LAS(lds + t * 8), 16, 0, 0);
}

// ---------------- fused fp32->fp16 converts + RoPE tables ----------------
__global__ void convall(const float* __restrict__ x, const float* __restrict__ wq,
                        const float* __restrict__ wk, const float* __restrict__ wv,
                        f16* __restrict__ xh, f16* __restrict__ wh,
                        float* __restrict__ cosT, float* __restrict__ sinT) {
  int bid = blockIdx.x;
  if (bid >= 3584) {  // RoPE tables [2048][32]
    int idx = (bid - 3584) * 256 + threadIdx.x;
    int n = idx >> 5, jj = idx & 31;
    float inv = powf(10000.0f, -(float)jj * (1.0f / 32.0f));
    float ang = (float)n * inv;
    cosT[idx] = cosf(ang);
    sinT[idx] = sinf(ang);
    return;
  }
  const float* s;
  f16* d;
  int boff;
  if (bid < 2048)      { s = x;  d = xh;            boff = bid; }
  else if (bid < 2560) { s = wq; d = wh;            boff = bid - 2048; }
  else if (bid < 3072) { s = wk; d = wh + 1048576;  boff = bid - 2560; }
  else                 { s = wv; d = wh + 2097152;  boff = bid - 3072; }
  int i = (boff * 256 + threadIdx.x) * 8;
  float4 a = *(const float4*)(s + i);
  float4 b = *(const float4*)(s + i + 4);
  f16x8 o = {(f16)a.x, (f16)a.y, (f16)a.z, (f16)a.w,
             (f16)b.x, (f16)b.y, (f16)b.z, (f16)b.w};
  *(f16x8*)(d + i) = o;
}

// ---------------- fused QKV GEMM + RoPE epilogue ----------------
// X: [4096][1024] f16, W: [3072][1024] f16 (Wq|Wk|Wv stacked)
// Q,K out: [32][2048][64] (RoPE applied, Q pre-scaled by log2e/8)
// Vt out:  [32][64][2048] with PERMUTED key coord n' = 32a+8c+4b+r
// (n = 32a+16b+4c+r) so attn's PV A-fragment is one contiguous b128.
__global__ __launch_bounds__(256, 3) void qkv_gemm(
    const f16* __restrict__ X, const f16* __restrict__ W,
    const float* __restrict__ cosT, const float* __restrict__ sinT,
    f16* __restrict__ Q, f16* __restrict__ K, f16* __restrict__ Vt) {
  __shared__ f16 As[128 * 64];
  __shared__ f16 Bs[128 * 64];
  const int tid = threadIdx.x;
  const int wv = tid >> 6, lane = tid & 63;
  const int m0 = blockIdx.x * 128, n0 = blockIdx.y * 128;
  const int cl = lane & 15, g = lane >> 4;
  const int wr = (wv >> 1) * 64, wc = (wv & 1) * 64;
  const int vx = cl & 7;

  f32x4 acc[4][4] = {};
  const f16* ga = X + (size_t)m0 * 1024;
  const f16* gb = W + (size_t)n0 * 1024;

  for (int kt = 0; kt < 1024; kt += 64) {
    __syncthreads();
#pragma unroll
    for (int rd = 0; rd < 4; ++rd) {
      stage_tile(ga + kt, 1024, As, tid + rd * 256);
      stage_tile(gb + kt, 1024, Bs, tid + rd * 256);
    }
    __syncthreads();  // compiler drains vmcnt before barrier
#pragma unroll
    for (int kk = 0; kk < 2; ++kk) {
      f16x8 a[4], bf[4];
#pragma unroll
      for (int mi = 0; mi < 4; ++mi)
        a[mi] = *(const f16x8*)(As + (wr + mi * 16 + cl) * 64 +
                                (((kk * 4 + g) ^ vx) << 3));
#pragma unroll
      for (int ni = 0; ni < 4; ++ni)
        bf[ni] = *(const f16x8*)(Bs + (wc + ni * 16 + cl) * 64 +
                                 (((kk * 4 + g) ^ vx) << 3));
#pragma unroll
      for (int mi = 0; mi < 4; ++mi)
#pragma unroll
        for (int ni = 0; ni < 4; ++ni)
          acc[mi][ni] = mfma16(a[mi], bf[ni], acc[mi][ni]);
    }
  }

  // epilogue: C/D layout col=lane&15 row=(lane>>4)*4+reg
  const int p = n0 >> 10;  // 0=q 1=k 2=v
  for (int mi = 0; mi < 4; ++mi) {
    int rbase = m0 + wr + mi * 16 + g * 4;
    for (int ni = 0; ni < 4; ++ni) {
      int gc = n0 + wc + ni * 16 + cl;
      int f = gc & 1023;
      int h = f >> 6, d = f & 63;
      if (p < 2) {
        int j = d >> 1;
        f16* dst = (p == 0) ? Q : K;
        // Q pre-scale folds softmax 1/8 and log2(e) (exp2-domain scores)
        float sc = (p == 0) ? 0.18033688011f : 1.0f;
        for (int r = 0; r < 4; ++r) {
          int row = rbase + r;
          int bb = row >> 11, n = row & 2047;
          float co = cosT[n * 32 + j], si = sinT[n * 32 + j];
          float v = acc[mi][ni][r];
          float pr = __shfl_xor(v, 1);
          float o = (d & 1) ? (v * co + pr * si) : (v * co - pr * si);
          dst[((bb * 16 + h) * 2048 + n) * 64 + d] = (f16)(o * sc);
        }
      } else {
        int bb = rbase >> 11, n = rbase & 2047;
        // permuted key coord (4-aligned block): n' = 32a | 8c | 4b
        int np = (n & ~31) | (((n >> 2) & 3) << 3) | (((n >> 4) & 1) << 2);
        f16x4 pk = {(f16)acc[mi][ni][0], (f16)acc[mi][ni][1],
                    (f16)acc[mi][ni][2], (f16)acc[mi][ni][3]};
        *(f16x4*)(Vt + (size_t)((bb * 16 + h) * 64 + d) * 2048 + np) = pk;
      }
    }
  }
}

// ---------------- flash attention fwd v7 ----------------
// grid 1024 x 128 thr; block = 64 q (2 waves x 32 q), KVBLK=64.
// 4 independent blocks/CU (4 barrier domains) -> cross-block latency hiding.
// Double-buffered K/V, unroll-2 loop (static LDS addrs), counted vmcnt(8).
// Static-max softmax p = 2^s; P in-register; V key-permuted (b128 A-frags).
__global__ __launch_bounds__(128, 2) void attn(
    const f16* __restrict__ Q, const f16* __restrict__ K,
    const f16* __restrict__ Vt, float* __restrict__ out) {
  __shared__ f16 KB0[4096], VB0[4096], KB1[4096], VB1[4096];
  const int tid = threadIdx.x;            // 0..127
  const int w = tid >> 6, lane = tid & 63;
  const int cl = lane & 15, g = lane >> 4;
  const int id = blockIdx.x;              // 0..1023
  const int xcd = id & 7, j = id >> 3;    // XCD-grouped: 4 bh per XCD
  const int bh = xcd * 4 + (j >> 5);
  const int b = bh >> 4, h = bh & 15;
  const int qb = (j & 31) * 64 + w * 32;  // wave's 32-q base
  const f16* Qp = Q + (size_t)bh * (2048 * 64);
  const f16* Kp = K + (size_t)bh * (2048 * 64);
  const f16* Vp = Vt + (size_t)bh * (64 * 2048);

  // Q as B-operand: col=q=cl (per half), k=d (pre-scaled by log2e/8)
  f16x8 bq[2][2];
#pragma unroll
  for (int qh = 0; qh < 2; ++qh) {
    bq[qh][0] = *(const f16x8*)(Qp + (qb + qh * 16 + cl) * 64 + g * 8);
    bq[qh][1] = *(const f16x8*)(Qp + (qb + qh * 16 + cl) * 64 + 32 + g * 8);
  }

  f32x4 acc[2][4] = {};   // acc[qh][dblk]: O^T[d=dblk*16+g*4+r][q]
  float lsp[2] = {0.f, 0.f};
  const int vx = cl & 7;
  const f32x4 z4 = {0.f, 0.f, 0.f, 0.f};

  auto STAGE = [&](int it, f16* kb, f16* vb) {
    const f16* kp = Kp + (size_t)it * 4096;
    const f16* vp = Vp + (size_t)it * 64;
#pragma unroll
    for (int rd = 0; rd < 4; ++rd) stage_tile(kp, 64, kb, tid + rd * 128);
#pragma unroll
    for (int rd = 0; rd < 4; ++rd) stage_tile(vp, 2048, vb, tid + rd * 128);
  };

  auto COMP = [&](const f16* kb, const f16* vb) {
    // K fragments (shared by both q-halves)
    f16x8 a0[4], a1[4];
#pragma unroll
    for (int i = 0; i < 4; ++i) {
      const f16* kr = kb + (i * 16 + cl) * 64;
      a0[i] = *(const f16x8*)(kr + ((g ^ vx) << 3));
      a1[i] = *(const f16x8*)(kr + (((4 + g) ^ vx) << 3));
    }
    // QK^T (swapped): s[qh][i] rows = keys i*16+g*4+r, col = q
    f32x4 s[2][4];
    __builtin_amdgcn_s_setprio(1);
#pragma unroll
    for (int qh = 0; qh < 2; ++qh)
#pragma unroll
      for (int i = 0; i < 4; ++i)
        s[qh][i] = mfma16(a1[i], bq[qh][1], mfma16(a0[i], bq[qh][0], z4));
    __builtin_amdgcn_s_setprio(0);
    // static-max softmax p = 2^s; packed cvt into PV B-operands
    union PB { f16x8 v; f16x2 hx[4]; };
    PB pbu[2][2];  // [qh][ks]
#pragma unroll
    for (int qh = 0; qh < 2; ++qh) {
      float ps = 0.f;
#pragma unroll
      for (int i = 0; i < 4; ++i) {
        float p0 = exp2f(s[qh][i][0]);
        float p1 = exp2f(s[qh][i][1]);
        float p2 = exp2f(s[qh][i][2]);
        float p3 = exp2f(s[qh][i][3]);
        ps += (p0 + p1) + (p2 + p3);
        pbu[qh][i >> 1].hx[(i & 1) * 2] = cvt2(p0, p1);
        pbu[qh][i >> 1].hx[(i & 1) * 2 + 1] = cvt2(p2, p3);
      }
      lsp[qh] += ps;
    }
    // PV: single b128 A-frag per (ks,d) thanks to V key-permutation
    __builtin_amdgcn_s_setprio(1);
#pragma unroll
    for (int ks = 0; ks < 2; ++ks) {
#pragma unroll
      for (int d = 0; d < 4; ++d) {
        const f16* vr = vb + (d * 16 + cl) * 64;
        f16x8 va = *(const f16x8*)(vr + (((ks * 4 + g) ^ vx) << 3));
        acc[0][d] = mfma16(va, pbu[0][ks].v, acc[0][d]);
        acc[1][d] = mfma16(va, pbu[1][ks].v, acc[1][d]);
      }
    }
    __builtin_amdgcn_s_setprio(0);
  };

  // prologue: tiles 0 and 1 (8 VMEM per wave per tile)
  STAGE(0, KB0, VB0);
  STAGE(1, KB1, VB1);

  for (int t = 0; t < 15; ++t) {
    // tile 2t (buf 0): landed when outstanding <= 8 (in-order retirement)
    asm volatile("s_waitcnt vmcnt(8)" ::: "memory");
    __builtin_amdgcn_s_barrier();
    COMP(KB0, VB0);
    __builtin_amdgcn_s_barrier();   // all waves done reading buf0
    STAGE(2 * t + 2, KB0, VB0);
    // tile 2t+1 (buf 1)
    asm volatile("s_waitcnt vmcnt(8)" ::: "memory");
    __builtin_amdgcn_s_barrier();
    COMP(KB1, VB1);
    __builtin_amdgcn_s_barrier();
    STAGE(2 * t + 3, KB1, VB1);
  }
  // tiles 30, 31 (no more staging)
  asm volatile("s_waitcnt vmcnt(8)" ::: "memory");
  __builtin_amdgcn_s_barrier();
  COMP(KB0, VB0);
  asm volatile("s_waitcnt vmcnt(0)" ::: "memory");
  __builtin_amdgcn_s_barrier();
  COMP(KB1, VB1);

#pragma unroll
  for (int qh = 0; qh < 2; ++qh) {
    float ls = lsp[qh];
    ls += __shfl_xor(ls, 16);
    ls += __shfl_xor(ls, 32);
    float inv = 1.0f / ls;
    float* ob = out + (size_t)(b * 2048 + qb + qh * 16 + cl) * 1024 +
                h * 64 + g * 4;
#pragma unroll
    for (int d = 0; d < 4; ++d) {
      float4 o = {acc[qh][d][0] * inv, acc[qh][d][1] * inv,
                  acc[qh][d][2] * inv, acc[qh][d][3] * inv};
      *(float4*)(ob + (size_t)d * 16) = o;
    }
  }
}

extern "C" void kernel_launch(void* const* d_in, const int* in_sizes, int n_in,
                              void* d_out, int out_size, void* d_ws, size_t ws_size,
                              hipStream_t stream) {
  const float* x  = (const float*)d_in[0];
  const float* Wq = (const float*)d_in[1];
  const float* Wk = (const float*)d_in[2];
  const float* Wv = (const float*)d_in[3];
  float* out = (float*)d_out;
  char* ws = (char*)d_ws;

  f16* xh   = (f16*)(ws);                       // 8388608 B
  f16* wh   = (f16*)(ws + 8388608);             // 6291456 B
  f16* Qr   = (f16*)(ws + 14680064);            // 8388608 B
  f16* Kr   = (f16*)(ws + 23068672);            // 8388608 B
  f16* Vt   = (f16*)(ws + 31457280);            // 8388608 B
  float* cosT = (float*)(ws + 39845888);        // 262144 B
  float* sinT = (float*)(ws + 40108032);        // total ~40.4 MB

  convall<<<3840, 256, 0, stream>>>(x, Wq, Wk, Wv, xh, wh, cosT, sinT);

  dim3 g1(32, 24);
  qkv_gemm<<<g1, 256, 0, stream>>>(xh, wh, cosT, sinT, Qr, Kr, Vt);

  attn<<<1024, 128, 0, stream>>>(Qr, Kr, Vt, out);
}